// Round 2
// baseline (1596.212 us; speedup 1.0000x reference)
//
#include <hip/hip_runtime.h>
#include <hip/hip_bf16.h>

// Problem constants (B,S,E,H,D) = (2, 2048, 1024, 16, 64)
#define BB 2
#define SS 2048
#define EE 1024
#define HH 16
#define DD 64

constexpr int BM = 64, BN = 64, BK = 16;

// ---------------------------------------------------------------------------
// Generic fp32 tile GEMM: C[m,n] = scale * sum_k A[m,k] * B[k,n] (+ bias[n])
// A is row-major [M,K] (lda), B is row-major [K,N] (ldb) or, if TRANSB,
// row-major [N,K] (ldb). Cbase points at this block's (m0,n0) tile origin.
// All dims are multiples of the tile sizes for this problem -> no bounds checks.
// ---------------------------------------------------------------------------
template<bool TRANSB>
__device__ __forceinline__ void gemm_tile(
    const float* __restrict__ A, int lda,
    const float* __restrict__ B, int ldb,
    const float* __restrict__ bias,
    float* __restrict__ Cbase, int ldc,
    int K, float scale, int m0, int n0)
{
    __shared__ float As[BK][BM + 4];   // stored transposed: As[k][m]
    __shared__ float Bs[BK][BN + 4];   // Bs[k][n]

    const int tid = threadIdx.x;
    const int tx = tid & 15;           // 16 col-groups
    const int ty = tid >> 4;           // 16 row-groups

    // global-load indices
    const int a_m = tid >> 2;          // 0..63
    const int a_k = (tid & 3) * 4;     // 0,4,8,12
    const int b_r = tid >> 4;          // 0..15
    const int b_c = (tid & 15) * 4;    // 0..60

    float acc[4][4] = {};

    for (int k0 = 0; k0 < K; k0 += BK) {
        // A tile: each thread one float4, scatter-transpose into LDS
        const float4 av = *(const float4*)&A[(size_t)(m0 + a_m) * lda + k0 + a_k];
        As[a_k + 0][a_m] = av.x;
        As[a_k + 1][a_m] = av.y;
        As[a_k + 2][a_m] = av.z;
        As[a_k + 3][a_m] = av.w;
        if (!TRANSB) {
            const float4 bv = *(const float4*)&B[(size_t)(k0 + b_r) * ldb + n0 + b_c];
            *(float4*)&Bs[b_r][b_c] = bv;
        } else {
            const float4 bv = *(const float4*)&B[(size_t)(n0 + a_m) * ldb + k0 + a_k];
            Bs[a_k + 0][a_m] = bv.x;
            Bs[a_k + 1][a_m] = bv.y;
            Bs[a_k + 2][a_m] = bv.z;
            Bs[a_k + 3][a_m] = bv.w;
        }
        __syncthreads();

        #pragma unroll
        for (int kk = 0; kk < BK; ++kk) {
            const float4 a  = *(const float4*)&As[kk][ty * 4];
            const float4 bq = *(const float4*)&Bs[kk][tx * 4];
            acc[0][0] = fmaf(a.x, bq.x, acc[0][0]);
            acc[0][1] = fmaf(a.x, bq.y, acc[0][1]);
            acc[0][2] = fmaf(a.x, bq.z, acc[0][2]);
            acc[0][3] = fmaf(a.x, bq.w, acc[0][3]);
            acc[1][0] = fmaf(a.y, bq.x, acc[1][0]);
            acc[1][1] = fmaf(a.y, bq.y, acc[1][1]);
            acc[1][2] = fmaf(a.y, bq.z, acc[1][2]);
            acc[1][3] = fmaf(a.y, bq.w, acc[1][3]);
            acc[2][0] = fmaf(a.z, bq.x, acc[2][0]);
            acc[2][1] = fmaf(a.z, bq.y, acc[2][1]);
            acc[2][2] = fmaf(a.z, bq.z, acc[2][2]);
            acc[2][3] = fmaf(a.z, bq.w, acc[2][3]);
            acc[3][0] = fmaf(a.w, bq.x, acc[3][0]);
            acc[3][1] = fmaf(a.w, bq.y, acc[3][1]);
            acc[3][2] = fmaf(a.w, bq.z, acc[3][2]);
            acc[3][3] = fmaf(a.w, bq.w, acc[3][3]);
        }
        __syncthreads();
    }

    #pragma unroll
    for (int i = 0; i < 4; ++i) {
        float4 r;
        r.x = acc[i][0] * scale;
        r.y = acc[i][1] * scale;
        r.z = acc[i][2] * scale;
        r.w = acc[i][3] * scale;
        if (bias) {
            r.x += bias[n0 + tx * 4 + 0];
            r.y += bias[n0 + tx * 4 + 1];
            r.z += bias[n0 + tx * 4 + 2];
            r.w += bias[n0 + tx * 4 + 3];
        }
        *(float4*)&Cbase[(size_t)(ty * 4 + i) * ldc + tx * 4] = r;
    }
}

// ---------------------------------------------------------------------------
// 1) Projections: qh = split(q@wq+bq), kh = split(k@wq+bq)  [source bug: wq!],
//    vh = split(v@wv+bv).  Output layout [B,H,S,D].
// ---------------------------------------------------------------------------
__global__ __launch_bounds__(256) void proj_kernel(
    const float* __restrict__ q, const float* __restrict__ k,
    const float* __restrict__ v,
    const float* __restrict__ wq_w, const float* __restrict__ wq_b,
    const float* __restrict__ wv_w, const float* __restrict__ wv_b,
    float* __restrict__ qh, float* __restrict__ kh, float* __restrict__ vh)
{
    const int m0 = blockIdx.x * BM;
    const int n0 = blockIdx.y * BN;
    const int z  = blockIdx.z;
    const float* A  = (z == 0) ? q : (z == 1) ? k : v;
    const float* W  = (z == 2) ? wv_w : wq_w;
    const float* bb = (z == 2) ? wv_b : wq_b;
    float* dst      = (z == 0) ? qh : (z == 1) ? kh : vh;
    const int b  = m0 / SS;
    const int s0 = m0 % SS;
    const int h  = n0 / DD;          // BN == DD: one head per n-tile
    float* Cbase = dst + ((size_t)(b * HH + h) * SS + s0) * DD;
    gemm_tile<false>(A, EE, W, EE, bb, Cbase, DD, EE, 1.0f, m0, n0);
}

// ---------------------------------------------------------------------------
// 2) Logits: attn_raw[bh, i, j] = (qh . kh) / sqrt(D)   (to d_out attn area)
// ---------------------------------------------------------------------------
__global__ __launch_bounds__(256) void qk_kernel(
    const float* __restrict__ qh, const float* __restrict__ kh,
    float* __restrict__ attn)
{
    const int m0 = blockIdx.x * BM;
    const int n0 = blockIdx.y * BN;
    const int bh = blockIdx.z;
    const float* A  = qh + (size_t)bh * SS * DD;
    const float* Bm = kh + (size_t)bh * SS * DD;
    float* Cbase = attn + (size_t)bh * SS * SS + (size_t)m0 * SS + n0;
    gemm_tile<true>(A, DD, Bm, DD, nullptr, Cbase, SS, DD, 0.125f, m0, n0);
}

// ---------------------------------------------------------------------------
// 3) Row softmax in place over attn (adds mask * -1e9 first). One block per row.
// ---------------------------------------------------------------------------
__global__ __launch_bounds__(256) void softmax_kernel(
    float* __restrict__ attn, const float* __restrict__ mask)
{
    const int r = blockIdx.x;                 // 0 .. B*H*S-1
    const int b = r / (HH * SS);
    float* row = attn + (size_t)r * SS;
    const float* mrow = mask + (size_t)b * SS;
    const int t = threadIdx.x;

    float4 v0 = *(const float4*)&row[t * 4];
    float4 v1 = *(const float4*)&row[1024 + t * 4];
    const float4 mk0 = *(const float4*)&mrow[t * 4];
    const float4 mk1 = *(const float4*)&mrow[1024 + t * 4];
    v0.x += mk0.x * -1e9f; v0.y += mk0.y * -1e9f;
    v0.z += mk0.z * -1e9f; v0.w += mk0.w * -1e9f;
    v1.x += mk1.x * -1e9f; v1.y += mk1.y * -1e9f;
    v1.z += mk1.z * -1e9f; v1.w += mk1.w * -1e9f;

    float mx = fmaxf(fmaxf(fmaxf(v0.x, v0.y), fmaxf(v0.z, v0.w)),
                     fmaxf(fmaxf(v1.x, v1.y), fmaxf(v1.z, v1.w)));
    #pragma unroll
    for (int off = 32; off; off >>= 1)
        mx = fmaxf(mx, __shfl_xor(mx, off));

    __shared__ float red[8];
    if ((t & 63) == 0) red[t >> 6] = mx;
    __syncthreads();
    mx = fmaxf(fmaxf(red[0], red[1]), fmaxf(red[2], red[3]));

    v0.x = __expf(v0.x - mx); v0.y = __expf(v0.y - mx);
    v0.z = __expf(v0.z - mx); v0.w = __expf(v0.w - mx);
    v1.x = __expf(v1.x - mx); v1.y = __expf(v1.y - mx);
    v1.z = __expf(v1.z - mx); v1.w = __expf(v1.w - mx);

    float sm = v0.x + v0.y + v0.z + v0.w + v1.x + v1.y + v1.z + v1.w;
    #pragma unroll
    for (int off = 32; off; off >>= 1)
        sm += __shfl_xor(sm, off);
    if ((t & 63) == 0) red[4 + (t >> 6)] = sm;
    __syncthreads();
    sm = red[4] + red[5] + red[6] + red[7];

    const float inv = 1.0f / sm;
    v0.x *= inv; v0.y *= inv; v0.z *= inv; v0.w *= inv;
    v1.x *= inv; v1.y *= inv; v1.z *= inv; v1.w *= inv;
    *(float4*)&row[t * 4] = v0;
    *(float4*)&row[1024 + t * 4] = v1;
}

// ---------------------------------------------------------------------------
// 4) ctx = attn @ vh, stored as [B,S,E] with head h in columns h*D..h*D+63
// ---------------------------------------------------------------------------
__global__ __launch_bounds__(256) void pv_kernel(
    const float* __restrict__ attn, const float* __restrict__ vh,
    float* __restrict__ ctx)
{
    const int m0 = blockIdx.x * BM;
    const int bh = blockIdx.z;
    const int b = bh / HH, h = bh % HH;
    const float* A  = attn + (size_t)bh * SS * SS;
    const float* Bm = vh + (size_t)bh * SS * DD;
    float* Cbase = ctx + ((size_t)b * SS + m0) * EE + h * DD;
    gemm_tile<false>(A, SS, Bm, DD, nullptr, Cbase, EE, SS, 1.0f, m0, 0);
}

// ---------------------------------------------------------------------------
// 5) out = ctx @ wo + bo
// ---------------------------------------------------------------------------
__global__ __launch_bounds__(256) void out_kernel(
    const float* __restrict__ ctx, const float* __restrict__ wo_w,
    const float* __restrict__ wo_b, float* __restrict__ out)
{
    const int m0 = blockIdx.x * BM;
    const int n0 = blockIdx.y * BN;
    gemm_tile<false>(ctx, EE, wo_w, EE, wo_b,
                     out + (size_t)m0 * EE + n0, EE, EE, 1.0f, m0, n0);
}

extern "C" void kernel_launch(void* const* d_in, const int* in_sizes, int n_in,
                              void* d_out, int out_size, void* d_ws, size_t ws_size,
                              hipStream_t stream)
{
    (void)in_sizes; (void)n_in; (void)out_size; (void)ws_size;
    const float* v    = (const float*)d_in[0];
    const float* k    = (const float*)d_in[1];
    const float* q    = (const float*)d_in[2];
    const float* mask = (const float*)d_in[3];
    const float* wq_w = (const float*)d_in[4];
    const float* wq_b = (const float*)d_in[5];
    const float* wv_w = (const float*)d_in[6];
    const float* wv_b = (const float*)d_in[7];
    const float* wo_w = (const float*)d_in[8];
    const float* wo_b = (const float*)d_in[9];

    float* outp = (float*)d_out;                       // [B,S,E]
    float* attn = outp + (size_t)BB * SS * EE;         // [B,H,S,S]

    float* ws  = (float*)d_ws;
    float* qh  = ws;                                   // [B,H,S,D]
    float* kh  = ws + (size_t)BB * HH * SS * DD;       // [B,H,S,D]
    float* vh  = ws + (size_t)2 * BB * HH * SS * DD;   // [B,H,S,D]
    float* ctx = ws + (size_t)3 * BB * HH * SS * DD;   // [B,S,E]

    const dim3 blk(256);
    proj_kernel<<<dim3(64, 16, 3), blk, 0, stream>>>(q, k, v, wq_w, wq_b,
                                                     wv_w, wv_b, qh, kh, vh);
    qk_kernel<<<dim3(32, 32, 32), blk, 0, stream>>>(qh, kh, attn);
    softmax_kernel<<<dim3(BB * HH * SS), blk, 0, stream>>>(attn, mask);
    pv_kernel<<<dim3(32, 1, 32), blk, 0, stream>>>(attn, vh, ctx);
    out_kernel<<<dim3(64, 16, 1), blk, 0, stream>>>(ctx, wo_w, wo_b, outp);
}